// Round 4
// baseline (364.727 us; speedup 1.0000x reference)
//
#include <hip/hip_runtime.h>
#include <hip/hip_bf16.h>

// SynthesisBlock: modulated 3x3 conv (StyleGAN2-style) on MI355X.
// R4: X read directly global->VGPR from a px-tiled padded layout (xs2);
//     LDS holds only W (double-buffered, 1 barrier/step, stage||compute).
//     R2's XCD swizzle restored (8 cot-blocks sharing an X tile -> same XCD).

typedef float f32x4 __attribute__((ext_vector_type(4)));
typedef short bf16x8 __attribute__((ext_vector_type(8)));
typedef int i32x4 __attribute__((ext_vector_type(4)));

#define BB 16
#define CIN 512
#define COUT 512
#define HH 64
#define WW 64
#define LL 512

// xs2 layout: per (b,y) row of 81920 B: [oct=ci>>3 (64)][xt=0..4][sub=0..15][j=0..7]
//   byte off = oct*1280 + ((x+8)>>4)*256 + ((x+8)&15)*16 + (ci&7)*2
// px p = x+8 in [0,80); p<8 and p>=72 are zero pads.
#define XS2ROWB 81920

// ws layout (bytes)
#define XS2_OFF 0
#define XS2_SZ (BB * HH * XS2ROWB)               // 83886080
#define WT_OFF (XS2_OFF + XS2_SZ)
#define WT_SZ (9 * COUT * CIN * 2)               // 4718592
#define STYLE_OFF (WT_OFF + WT_SZ)
#define STYLE_SZ (BB * CIN * 4)
#define WSQ_OFF (STYLE_OFF + STYLE_SZ)
#define WSQ_SZ (COUT * CIN * 4)
#define DEM_OFF (WSQ_OFF + WSQ_SZ)
#define DEM_SZ (BB * COUT * 4)
#define ZROW_OFF (DEM_OFF + DEM_SZ)
#define ZROW_SZ XS2ROWB
#define WS_NEEDED (ZROW_OFF + ZROW_SZ)           // ~89.8 MB

// conv LDS: W only, double-buffered. Per buffer: 9 taps x 64co x 64B = 36864.
#define WBUF 36864
#define LDSZ (2 * WBUF)                          // 73728 -> 2 blocks/CU

__device__ __forceinline__ void gld_lds16(const void* g, void* l) {
  __builtin_amdgcn_global_load_lds(
      (const __attribute__((address_space(1))) unsigned int*)g,
      (__attribute__((address_space(3))) unsigned int*)l, 16, 0, 0);
}

// ---------------- K1: style ----------------
__global__ void style_kernel(const float* __restrict__ latent,
                             const float* __restrict__ affine_w,
                             const float* __restrict__ affine_b,
                             float* __restrict__ style) {
  const int idx = blockIdx.x * 256 + threadIdx.x;   // 8192
  const int b = idx >> 9, ci = idx & 511;
  const float* lp = latent + b * LL;
  const float* wp = affine_w + ci * LL;
  float acc = 0.f;
  for (int l = 0; l < LL; ++l) acc += lp[l] * wp[l];
  style[idx] = acc * 0.044194173824159216f + affine_b[ci];  // sqrt(1/512)
}

// ---------------- K2: weight sumsq + bf16 tap-major transform ----------------
__global__ void wprep_kernel(const float* __restrict__ conv_w,
                             float* __restrict__ wsq,
                             __hip_bfloat16* __restrict__ wt) {
  const int idx = blockIdx.x * 256 + threadIdx.x;   // 262144 = co*512+ci
  const int co = idx >> 9, ci = idx & 511;
  const float* wp = conv_w + idx * 9;
  float ss = 0.f;
#pragma unroll
  for (int t = 0; t < 9; ++t) {
    float v = wp[t];
    ss += v * v;
    wt[(t * COUT + co) * CIN + ci] = __float2bfloat16(v);
  }
  wsq[idx] = ss;
}

// ---------------- K3: demodulation scale ----------------
__global__ void dem_kernel(const float* __restrict__ wsq,
                           const float* __restrict__ style,
                           float* __restrict__ dem) {
  const int idx = blockIdx.x * 256 + threadIdx.x;   // 8192 = b*512+co
  const int b = idx >> 9, co = idx & 511;
  const float* sp = style + b * CIN;
  const float* wp = wsq + co * CIN;
  float acc = 0.f;
  for (int ci = 0; ci < CIN; ++ci) {
    float s = sp[ci];
    acc += wp[ci] * s * s;
  }
  dem[idx] = 1.0f / sqrtf(acc + 1e-8f);
}

// ---------------- K4: modulate + transpose to px-tiled bf16 (xs2) ----------------
__global__ void xsprep_kernel(const float* __restrict__ content,
                              const float* __restrict__ style,
                              __hip_bfloat16* __restrict__ xs2,
                              __hip_bfloat16* __restrict__ zrow) {
  const int tid = threadIdx.x;
  if (blockIdx.x == 1024) {  // zero the shared out-of-range row
    for (int off = tid * 16; off < XS2ROWB; off += 256 * 16)
      *(i32x4*)((char*)zrow + off) = (i32x4){0, 0, 0, 0};
    return;
  }
  __shared__ float tile[64][65];
  const int b = blockIdx.x >> 6;
  const int y = blockIdx.x & 63;
  char* row = (char*)xs2 + (size_t)((b << 6) + y) * XS2ROWB;

  // zero the px pads of this row: slots s<8 -> xt0/sub s; s>=8 -> xt4/sub s
  for (int k = 0; k < 4; ++k) {
    const int idx = tid + k * 256;          // 0..1023 = oct*16 + s
    const int oct = idx >> 4, s = idx & 15;
    const int off = oct * 1280 + (s < 8 ? s * 16 : 1024 + s * 16);
    *(i32x4*)(row + off) = (i32x4){0, 0, 0, 0};
  }

  for (int cb = 0; cb < 8; ++cb) {
    const int ci0 = cb * 64;
    __syncthreads();
    {
      const int x = tid & 63;
      const int c0 = tid >> 6;
#pragma unroll
      for (int p = 0; p < 16; ++p) {
        const int ci = p * 4 + c0;
        tile[ci][x] = content[((b * CIN + ci0 + ci) * HH + y) * WW + x];
      }
    }
    __syncthreads();
    {
      const int x = tid & 63;
      const int o4 = tid >> 6;
      const int px = x + 8;
      const int xoff = ((px >> 4) << 8) + ((px & 15) << 4);
#pragma unroll
      for (int oo = 0; oo < 2; ++oo) {
        const int oct = o4 * 2 + oo;        // 0..7 within this 64-ci group
        bf16x8 v;
#pragma unroll
        for (int j = 0; j < 8; ++j) {
          const float st = style[b * CIN + ci0 + oct * 8 + j];
          v[j] = __bfloat16_as_short(
              __float2bfloat16(tile[oct * 8 + j][x] * st));
        }
        *(bf16x8*)(row + (ci0 / 8 + oct) * 1280 + xoff) = v;
      }
    }
  }
}

// ---------------- K5: main MFMA conv ----------------
// grid: 1024 blocks (XCD-swizzled: 8 consecutive logical cot-blocks sharing an
// X tile land on one XCD), 256 threads (4 waves). Block: 64co x 8 rows.
// Wave wv owns rows y0+2wv..+1; A (W) from LDS (dbuf), B (X) global->VGPR.
__global__ __launch_bounds__(256, 2) void conv_kernel(
    const __hip_bfloat16* __restrict__ xs2,  // px-tiled, padded
    const __hip_bfloat16* __restrict__ wt,   // [9][COUT][CIN]
    const float* __restrict__ dem,           // [B][COUT]
    const float* __restrict__ noise,         // [B][1][H][W]
    const float* __restrict__ biasp,         // [COUT]
    const float* __restrict__ nwp,           // scalar
    const __hip_bfloat16* __restrict__ zrow, // 80KB zeros
    float* __restrict__ out) {
  __shared__ __attribute__((aligned(16))) char lds[2][WBUF];

  const int tid = threadIdx.x;
  const int lane = tid & 63;
  const int wv = tid >> 6;

  // R2 swizzle: XCD x runs cot=0..7 consecutively for fixed (b,yo).
  const int d = blockIdx.x;                 // 0..1023
  const int L = (d & 7) * 128 + (d >> 3);   // bijective
  const int cot = L & 7;
  const int yo = (L >> 3) & 7;
  const int b = L >> 6;
  const int co0 = cot << 6;
  const int y0 = yo << 3;

  const int l15 = lane & 15;
  const int kg = lane >> 4;
  const int xsub = lane >> 2;   // 0..15 within staged chunk
  const int slotl = lane & 3;   // 16B slot within 64B co block

  // A-fragment LDS read offsets (XOR swizzle on 16B ci-chunk slot)
  int aoff[4];
#pragma unroll
  for (int mf = 0; mf < 4; ++mf) {
    const int co_l = l15 + mf * 16;
    const int fs = (co_l & 3) ^ ((co_l >> 2) & 3);
    aoff[mf] = co_l * 64 + ((kg ^ fs) << 4);
  }

  // B global row pointers (4 rows: y0+2wv-1 .. y0+2wv+2); zrow for OOB
  const char* rp[4];
#pragma unroll
  for (int ir = 0; ir < 4; ++ir) {
    const int yg = y0 + 2 * wv - 1 + ir;
    rp[ir] = (yg >= 0 && yg < 64)
                 ? (const char*)xs2 + (size_t)((b << 6) + yg) * XS2ROWB
                 : (const char*)zrow;
  }
  // B per-lane byte offsets (include kg*1280; add cib*5120 per step)
  int voff[4][3];
#pragma unroll
  for (int q = 0; q < 4; ++q)
#pragma unroll
    for (int dx = 0; dx < 3; ++dx) {
      const int p = 7 + q * 16 + l15 + dx;  // px = x+8, x = q*16+l15+dx-1
      voff[q][dx] = kg * 1280 + ((p >> 4) << 8) + ((p & 15) << 4);
    }

  f32x4 acc[4][8];
#pragma unroll
  for (int mf = 0; mf < 4; ++mf)
#pragma unroll
    for (int nf = 0; nf < 8; ++nf) acc[mf][nf] = (f32x4){0.f, 0.f, 0.f, 0.f};

  // stage W chunk-set for ci-block cibs into wbuf (9 chunks per wave)
  auto stageW = [&](int cibs, char* wbuf) {
    const int ci0 = cibs * 32;
    for (int i = wv; i < 36; i += 4) {
      const int tap = i >> 2, q = i & 3;
      const int co = q * 16 + xsub;
      const int dcig = slotl ^ ((co & 3) ^ ((co >> 2) & 3));
      const __hip_bfloat16* g =
          wt + ((tap << 9) + co0 + co) * CIN + ci0 + dcig * 8;
      gld_lds16(g, wbuf + tap * 4096 + q * 1024);
    }
  };

  stageW(0, lds[0]);

#pragma unroll 2
  for (int cib = 0; cib < 16; ++cib) {
    __syncthreads();  // stage(cib) landed; buf[cib^1] free (readers done)
    if (cib < 15) stageW(cib + 1, lds[(cib + 1) & 1]);
    const char* wb = lds[cib & 1];
    const int cshift = cib * 5120;

#pragma unroll
    for (int dx = 0; dx < 3; ++dx) {
      bf16x8 a[3][4];
#pragma unroll
      for (int dy = 0; dy < 3; ++dy)
#pragma unroll
        for (int mf = 0; mf < 4; ++mf)
          a[dy][mf] = *(const bf16x8*)(wb + (dy * 3 + dx) * 4096 + aoff[mf]);
#pragma unroll
      for (int ir = 0; ir < 4; ++ir) {
        const char* rpc = rp[ir] + cshift;
        bf16x8 bq[4];
#pragma unroll
        for (int q = 0; q < 4; ++q)
          bq[q] = *(const bf16x8*)(rpc + voff[q][dx]);
#pragma unroll
        for (int dy = 0; dy < 3; ++dy) {
          const int r = ir - dy;
          if (r == 0 || r == 1) {
#pragma unroll
            for (int q = 0; q < 4; ++q)
#pragma unroll
              for (int mf = 0; mf < 4; ++mf)
                acc[mf][r * 4 + q] = __builtin_amdgcn_mfma_f32_16x16x32_bf16(
                    a[dy][mf], bq[q], acc[mf][r * 4 + q], 0, 0, 0);
          }
        }
      }
    }
  }

  // ---- epilogue: demod scale, noise, bias, lrelu*sqrt(2) ----
  const float nwv = nwp[0];
#pragma unroll
  for (int r = 0; r < 2; ++r) {
    const int y = y0 + 2 * wv + r;
    float nz[4];
#pragma unroll
    for (int q = 0; q < 4; ++q)
      nz[q] = nwv * noise[(b << 12) + (y << 6) + q * 16 + l15];

#pragma unroll
    for (int mf = 0; mf < 4; ++mf) {
      const int cobase = co0 + mf * 16 + kg * 4;
      const f32x4 dm = *(const f32x4*)(dem + (b << 9) + cobase);
      const f32x4 bs = *(const f32x4*)(biasp + cobase);
#pragma unroll
      for (int r2 = 0; r2 < 4; ++r2) {
        const int co = cobase + r2;
        float* op = out + ((((b << 9) + co) << 12) | (y << 6) | l15);
        const float dmv = dm[r2];
        const float bsv = bs[r2];
#pragma unroll
        for (int q = 0; q < 4; ++q) {
          float v = acc[mf][r * 4 + q][r2] * dmv + nz[q] + bsv;
          v = (v > 0.f ? v : 0.2f * v) * 1.41421356237309515f;
          op[q * 16] = v;
        }
      }
    }
  }
}

extern "C" void kernel_launch(void* const* d_in, const int* in_sizes, int n_in,
                              void* d_out, int out_size, void* d_ws, size_t ws_size,
                              hipStream_t stream) {
  const float* content  = (const float*)d_in[0];
  const float* latent   = (const float*)d_in[1];
  const float* noise    = (const float*)d_in[2];
  const float* affine_w = (const float*)d_in[3];
  const float* affine_b = (const float*)d_in[4];
  const float* conv_w   = (const float*)d_in[5];
  const float* bias     = (const float*)d_in[6];
  const float* nw       = (const float*)d_in[7];
  float* out = (float*)d_out;
  char* ws = (char*)d_ws;

  if (ws_size < (size_t)WS_NEEDED) return;

  __hip_bfloat16* xs2  = (__hip_bfloat16*)(ws + XS2_OFF);
  __hip_bfloat16* wt   = (__hip_bfloat16*)(ws + WT_OFF);
  float* style = (float*)(ws + STYLE_OFF);
  float* wsq   = (float*)(ws + WSQ_OFF);
  float* dem   = (float*)(ws + DEM_OFF);
  __hip_bfloat16* zrow = (__hip_bfloat16*)(ws + ZROW_OFF);

  style_kernel<<<dim3(32), dim3(256), 0, stream>>>(latent, affine_w, affine_b, style);
  wprep_kernel<<<dim3(1024), dim3(256), 0, stream>>>(conv_w, wsq, wt);
  dem_kernel<<<dim3(32), dim3(256), 0, stream>>>(wsq, style, dem);
  xsprep_kernel<<<dim3(1025), dim3(256), 0, stream>>>(content, style, xs2, zrow);
  conv_kernel<<<dim3(1024), dim3(256), 0, stream>>>(xs2, wt, dem, noise, bias, nw, zrow, out);
}

// Round 5
// 322.321 us; speedup vs baseline: 1.1316x; 1.1316x over previous
//
#include <hip/hip_runtime.h>
#include <hip/hip_bf16.h>

// SynthesisBlock: modulated 3x3 conv (StyleGAN2-style) on MI355X.
// R5: back to X+W LDS staging (R2 data plan), but:
//  - 2-phase counted schedule: stage(t+1) issued BEFORE compute(t), one
//    barrier/step, loads in flight during MFMA (T3 minimum, m248v2).
//  - 16-ci steps + mfma_f32_32x32x16_bf16 (K=16 native, higher FLOP/cyc).
//  - lane-linear LDS layouts (consecutive lanes -> consecutive 16B units).
//  - xs3 global layout has pre-zeroed halo rows (y=-1,64) -> branchless stage.

typedef float f32x4 __attribute__((ext_vector_type(4)));
typedef float f32x16 __attribute__((ext_vector_type(16)));
typedef short bf16x8 __attribute__((ext_vector_type(8)));
typedef int i32x4 __attribute__((ext_vector_type(4)));

#define BB 16
#define CIN 512
#define COUT 512
#define HH 64
#define WW 64
#define LL 512

// xs3: [b 16][c16 32][rowidx 66 (= y+1, rows -1..64)][h 2][px' 68][ci8 8]
//   bf16; row = 2176 B; px' = x+1 (x in [-1,67)); px' 0,65,66,67 zero pads;
//   rowidx 0 and 65 are zero rows.
#define X3ROWB 2176
#define X3C16B (66 * X3ROWB)            // 143616
#define X3BB (32 * X3C16B)              // 4595712
#define XS3_SZ (16 * X3BB)              // 73531392

// wt3: [cib 32][tap 9][h 2][co 512][ci8 8] bf16
#define WT3_STEPB 147456                 // 9*2*512*8*2
#define WT3_SZ (32 * WT3_STEPB)          // 4718592

#define XS3_OFF 0
#define WT3_OFF XS3_SZ
#define STYLE_OFF (WT3_OFF + WT3_SZ)
#define STYLE_SZ (BB * CIN * 4)
#define WSQ_OFF (STYLE_OFF + STYLE_SZ)
#define WSQ_SZ (COUT * CIN * 4)
#define DEM_OFF (WSQ_OFF + WSQ_SZ)
#define DEM_SZ (BB * COUT * 4)
#define WS_NEEDED (DEM_OFF + DEM_SZ)     // ~75.7 MB

// conv LDS: X dbuf 2x22528 (22 chunks, 21760 used) + W dbuf 2x18432
#define XSTEPB 22528
#define WSTEPB 18432

__device__ __forceinline__ void gld_lds16(const void* g, void* l) {
  __builtin_amdgcn_global_load_lds(
      (const __attribute__((address_space(1))) unsigned int*)g,
      (__attribute__((address_space(3))) unsigned int*)l, 16, 0, 0);
}

// ---------------- K1: style ----------------
__global__ void style_kernel(const float* __restrict__ latent,
                             const float* __restrict__ affine_w,
                             const float* __restrict__ affine_b,
                             float* __restrict__ style) {
  const int idx = blockIdx.x * 256 + threadIdx.x;   // 8192
  const int b = idx >> 9, ci = idx & 511;
  const float* lp = latent + b * LL;
  const float* wp = affine_w + ci * LL;
  float acc = 0.f;
  for (int l = 0; l < LL; ++l) acc += lp[l] * wp[l];
  style[idx] = acc * 0.044194173824159216f + affine_b[ci];  // sqrt(1/512)
}

// ---------------- K2: weight sumsq + wt3 layout ----------------
__global__ void wprep_kernel(const float* __restrict__ conv_w,
                             float* __restrict__ wsq,
                             __hip_bfloat16* __restrict__ wt3) {
  const int idx = blockIdx.x * 256 + threadIdx.x;   // 262144 = co*512+ci
  const int co = idx >> 9, ci = idx & 511;
  const float* wp = conv_w + idx * 9;
  const int cib = ci >> 4, h = (ci >> 3) & 1, ci8 = ci & 7;
  __hip_bfloat16* base = wt3 + (size_t)cib * 73728 + h * 4096 + co * 8 + ci8;
  float ss = 0.f;
#pragma unroll
  for (int t = 0; t < 9; ++t) {
    float v = wp[t];
    ss += v * v;
    base[t * 8192] = __float2bfloat16(v);
  }
  wsq[idx] = ss;
}

// ---------------- K3: demodulation scale ----------------
__global__ void dem_kernel(const float* __restrict__ wsq,
                           const float* __restrict__ style,
                           float* __restrict__ dem) {
  const int idx = blockIdx.x * 256 + threadIdx.x;   // 8192 = b*512+co
  const int b = idx >> 9, co = idx & 511;
  const float* sp = style + b * CIN;
  const float* wp = wsq + co * CIN;
  float acc = 0.f;
  for (int ci = 0; ci < CIN; ++ci) {
    float s = sp[ci];
    acc += wp[ci] * s * s;
  }
  dem[idx] = 1.0f / sqrtf(acc + 1e-8f);
}

// ---------------- K4: modulate + transpose to xs3 ----------------
__global__ void xsprep_kernel(const float* __restrict__ content,
                              const float* __restrict__ style,
                              char* __restrict__ xs3) {
  __shared__ float tile[64][65];
  const int b = blockIdx.x >> 6;
  const int y = blockIdx.x & 63;
  const int tid = threadIdx.x;
  char* bbase = xs3 + (size_t)b * X3BB;

  // zero px' pads {0,65,66,67} of own row (all 32 c16, both h): 256 units
  {
    const int c16 = tid >> 3, rest = tid & 7;
    const int h = rest >> 2, pp = rest & 3;
    const int px = (pp == 0) ? 0 : 64 + pp;
    *(i32x4*)(bbase + (size_t)c16 * X3C16B + (y + 1) * X3ROWB + h * 1088 +
              px * 16) = (i32x4){0, 0, 0, 0};
  }
  // edge blocks zero the halo rows (rowidx 0 / 65): 32 c16 * 136 units
  if (y == 0 || y == 63) {
    const int rowidx = (y == 0) ? 0 : 65;
#pragma unroll
    for (int k = 0; k < 17; ++k) {
      const int u = tid + k * 256;
      if (u < 4352) {
        const int c16 = u / 136, w = u - c16 * 136;
        *(i32x4*)(bbase + (size_t)c16 * X3C16B + rowidx * X3ROWB + w * 16) =
            (i32x4){0, 0, 0, 0};
      }
    }
  }

  for (int cb = 0; cb < 8; ++cb) {
    const int ci0 = cb * 64;
    __syncthreads();
    {
      const int x = tid & 63;
      const int c0 = tid >> 6;
#pragma unroll
      for (int p = 0; p < 16; ++p) {
        const int ci = p * 4 + c0;
        tile[ci][x] = content[((b * CIN + ci0 + ci) * HH + y) * WW + x];
      }
    }
    __syncthreads();
    {
      const int x = tid & 63;
      const int o4 = tid >> 6;
#pragma unroll
      for (int oo = 0; oo < 2; ++oo) {
        const int oct = o4 * 2 + oo;        // 0..7 within 64-ci group
        const int c16 = cb * 4 + (oct >> 1);
        const int h = oct & 1;
        bf16x8 v;
#pragma unroll
        for (int j = 0; j < 8; ++j) {
          const float st = style[b * CIN + ci0 + oct * 8 + j];
          v[j] = __bfloat16_as_short(
              __float2bfloat16(tile[oct * 8 + j][x] * st));
        }
        *(bf16x8*)(bbase + (size_t)c16 * X3C16B + (y + 1) * X3ROWB + h * 1088 +
                   (x + 1) * 16) = v;
      }
    }
  }
}

// ---------------- K5: main MFMA conv ----------------
// grid 1024 (16b x 8yo x 8cot, R2 XCD swizzle), 256 threads (4 waves).
// Block: 64co x 8rows x 64px. Wave wv: rows y0+2wv..+1, frags mf2 x r2 x q2
// of 32x32. 2-phase: stage(t+1) || compute(t), 1 barrier/step, 32 steps.
__global__ __launch_bounds__(256, 2) void conv_kernel(
    const char* __restrict__ xs3,
    const char* __restrict__ wt3,
    const float* __restrict__ dem,
    const float* __restrict__ noise,
    const float* __restrict__ biasp,
    const float* __restrict__ nwp,
    float* __restrict__ out) {
  __shared__ __attribute__((aligned(16))) char xlds[2][XSTEPB];
  __shared__ __attribute__((aligned(16))) char wlds[2][WSTEPB];

  const int tid = threadIdx.x;
  const int lane = tid & 63;
  const int wv = tid >> 6;
  const int l31 = lane & 31;
  const int hsel = lane >> 5;

  const int d = blockIdx.x;                 // 0..1023
  const int L = (d & 7) * 128 + (d >> 3);   // bijective XCD swizzle
  const int cot = L & 7;
  const int yo = (L >> 3) & 7;
  const int b = L >> 6;
  const int co0 = cot << 6;
  const int y0 = yo << 3;

  // X chunk sources (step 0): chunk c covers region bytes [c*1024, +1024),
  // region = rows (y0-1..y0+9) of (b, c16=0) => storage rows y0+row.
  const char* xsrc[6];
#pragma unroll
  for (int k = 0; k < 6; ++k) {
    const int c = wv + 4 * k;
    if (c < 22) {
      const int beta = c * 1024 + lane * 16;
      const int row = beta / X3ROWB;
      const int within = beta - row * X3ROWB;
      xsrc[k] = xs3 + (size_t)(b * 32) * X3C16B +
                (size_t)(y0 + row) * X3ROWB + within;
    } else {
      xsrc[k] = xs3;
    }
  }
  // W chunk sources (step 0): chunk c = tap*2+h; lane -> co0+lane
  const char* wsrc[5];
#pragma unroll
  for (int k = 0; k < 5; ++k) {
    const int c = wv + 4 * k;
    if (c < 18) {
      const int tap = c >> 1, h = c & 1;
      wsrc[k] = wt3 + tap * 16384 + h * 8192 + (co0 + lane) * 16;
    } else {
      wsrc[k] = wt3;
    }
  }

  const int abase0 = hsel * 1024 + l31 * 16;  // + tap*2048 + mf*512
  const int bbase0 = hsel * 1088 + l31 * 16;  // + row*2176 + (q*32+dx)*16
  const int xwrow = 2 * wv * X3ROWB;

  f32x16 acc[2][2][2];
#pragma unroll
  for (int mf = 0; mf < 2; ++mf)
#pragma unroll
    for (int r = 0; r < 2; ++r)
#pragma unroll
      for (int q = 0; q < 2; ++q)
#pragma unroll
        for (int e = 0; e < 16; ++e) acc[mf][r][q][e] = 0.f;

  auto stage = [&](int t, int bi) {
    char* xd = xlds[bi];
    char* wd = wlds[bi];
    const size_t xadv = (size_t)t * X3C16B;
    const size_t wadv = (size_t)t * WT3_STEPB;
#pragma unroll
    for (int k = 0; k < 6; ++k) {
      const int c = wv + 4 * k;
      if (c < 22) gld_lds16(xsrc[k] + xadv, xd + c * 1024);
    }
#pragma unroll
    for (int k = 0; k < 5; ++k) {
      const int c = wv + 4 * k;
      if (c < 18) gld_lds16(wsrc[k] + wadv, wd + c * 1024);
    }
  };

  stage(0, 0);
  __syncthreads();

  for (int t = 0; t < 32; ++t) {
    const int bi = t & 1;
    if (t < 31) stage(t + 1, bi ^ 1);   // loads in flight during compute
    const char* xb = xlds[bi];
    const char* wb = wlds[bi];
#pragma unroll
    for (int dx = 0; dx < 3; ++dx) {
      bf16x8 a[3][2];
#pragma unroll
      for (int dy = 0; dy < 3; ++dy)
#pragma unroll
        for (int mf = 0; mf < 2; ++mf)
          a[dy][mf] = *(const bf16x8*)(wb + (dy * 3 + dx) * 2048 + abase0 +
                                       mf * 512);
#pragma unroll
      for (int ir = 0; ir < 4; ++ir) {
        const char* rp = xb + xwrow + ir * X3ROWB;
        bf16x8 bq[2];
#pragma unroll
        for (int q = 0; q < 2; ++q)
          bq[q] = *(const bf16x8*)(rp + bbase0 + (q * 32 + dx) * 16);
#pragma unroll
        for (int dy = 0; dy < 3; ++dy) {
          const int r = ir - dy;
          if (r == 0 || r == 1) {
#pragma unroll
            for (int q = 0; q < 2; ++q)
#pragma unroll
              for (int mf = 0; mf < 2; ++mf)
                acc[mf][r][q] = __builtin_amdgcn_mfma_f32_32x32x16_bf16(
                    a[dy][mf], bq[q], acc[mf][r][q], 0, 0, 0);
          }
        }
      }
    }
    __syncthreads();   // staged(t+1) landed + all reads of buf bi done
  }

  // ---- epilogue: demod scale, noise, bias, lrelu*sqrt(2) ----
  const float nwv = nwp[0];
  float nz[2][2];
#pragma unroll
  for (int r = 0; r < 2; ++r) {
    const int y = y0 + 2 * wv + r;
#pragma unroll
    for (int q = 0; q < 2; ++q)
      nz[r][q] = nwv * noise[(b << 12) + (y << 6) + q * 32 + l31];
  }
#pragma unroll
  for (int mf = 0; mf < 2; ++mf)
#pragma unroll
    for (int reg = 0; reg < 16; ++reg) {
      const int coo = (reg & 3) + 8 * (reg >> 2) + 4 * hsel;
      const int co = co0 + mf * 32 + coo;
      const float dv = dem[(b << 9) + co];
      const float bv = biasp[co];
#pragma unroll
      for (int r = 0; r < 2; ++r) {
        const int y = y0 + 2 * wv + r;
#pragma unroll
        for (int q = 0; q < 2; ++q) {
          float v = acc[mf][r][q][reg] * dv + nz[r][q] + bv;
          v = (v > 0.f ? v : 0.2f * v) * 1.41421356237309515f;
          out[(((size_t)(b << 9) + co) << 12) + (y << 6) + q * 32 + l31] = v;
        }
      }
    }
}

extern "C" void kernel_launch(void* const* d_in, const int* in_sizes, int n_in,
                              void* d_out, int out_size, void* d_ws, size_t ws_size,
                              hipStream_t stream) {
  const float* content  = (const float*)d_in[0];
  const float* latent   = (const float*)d_in[1];
  const float* noise    = (const float*)d_in[2];
  const float* affine_w = (const float*)d_in[3];
  const float* affine_b = (const float*)d_in[4];
  const float* conv_w   = (const float*)d_in[5];
  const float* bias     = (const float*)d_in[6];
  const float* nw       = (const float*)d_in[7];
  float* out = (float*)d_out;
  char* ws = (char*)d_ws;

  if (ws_size < (size_t)WS_NEEDED) return;

  char* xs3 = ws + XS3_OFF;
  __hip_bfloat16* wt3 = (__hip_bfloat16*)(ws + WT3_OFF);
  float* style = (float*)(ws + STYLE_OFF);
  float* wsq   = (float*)(ws + WSQ_OFF);
  float* dem   = (float*)(ws + DEM_OFF);

  style_kernel<<<dim3(32), dim3(256), 0, stream>>>(latent, affine_w, affine_b, style);
  wprep_kernel<<<dim3(1024), dim3(256), 0, stream>>>(conv_w, wsq, wt3);
  dem_kernel<<<dim3(32), dim3(256), 0, stream>>>(wsq, style, dem);
  xsprep_kernel<<<dim3(1024), dim3(256), 0, stream>>>(content, style, xs3);
  conv_kernel<<<dim3(1024), dim3(256), 0, stream>>>(
      xs3, (const char*)(ws + WT3_OFF), dem, noise, bias, nw, out);
}